// Round 5
// baseline (1440.611 us; speedup 1.0000x reference)
//
#include <hip/hip_runtime.h>

// 3-layer LSTM (T=1024,B=512,F=32,H1=32,H2=8,H3=8) + locked dropout.
//
// R5: SPILL ELIMINATION. R2-R4 declared ~184 floats/lane of weight arrays but
// VGPR_Count read 124-136 -> compiler was spilling weights to scratch and
// re-reading them EVERY timestep (explains 2266 cyc/step vs ~1200 paper model,
// and why R4's extra pressure regressed). Fix: precompute the feed-forward
// Wih1*x projection for all T into d_ws (kernel A, memory-bound GEMM), so the
// recurrent kernel (B) holds only 120 weight floats -> no spills, 64 fewer
// FMA insts/step, zero x LDS traffic. Serial R3 structure retained (skew was
// a regression; retry only once spills are confirmed dead).
// Fallback to the R3-style kernel if ws_size < 256 MB.

constexpr int T = 1024, B = 512, F = 32;
constexpr int H1 = 32, H2 = 8, H3 = 8;
constexpr int G1 = 4 * H1;  // 128 gate rows, layer 1

#define WAVE_SYNC() asm volatile("" ::: "memory")

#if __has_builtin(__builtin_amdgcn_rcpf)
#define RCPF(x) __builtin_amdgcn_rcpf(x)
#else
#define RCPF(x) (1.0f / (x))
#endif
#if __has_builtin(__builtin_amdgcn_exp2f)
#define EXP2F(x) __builtin_amdgcn_exp2f(x)
#else
#define EXP2F(x) exp2f(x)
#endif

#define SIG_CM (-1.4426950408889634f)

__device__ __forceinline__ float act_f(float v, float cm, float ka, float kb) {
    return fmaf(ka, RCPF(1.0f + EXP2F(v * cm)), kb);
}
__device__ __forceinline__ float tanh_fast(float v) {
    return fmaf(2.0f, RCPF(1.0f + EXP2F(v * (2.0f * SIG_CM))), -1.0f);
}

// macro params avoid float4 member names x/y/z/w (R1 lesson)
#define FMA4(ACC, WARR, VEC, BASE)                                             \
    ACC = fmaf(WARR[(BASE) + 0], VEC.x, ACC);                                  \
    ACC = fmaf(WARR[(BASE) + 1], VEC.y, ACC);                                  \
    ACC = fmaf(WARR[(BASE) + 2], VEC.z, ACC);                                  \
    ACC = fmaf(WARR[(BASE) + 3], VEC.w, ACC);

// ---------------------------------------------------------------------------
// Kernel A: xg[(t*B+b)*128 + r] = sum_k Wih1[r][k]*x[t][b][k] + bih1[r]+bhh1[r]
// Memory-bound (~320 MB traffic). Block=256 thr, 8 (t,b) pairs per block;
// thread (p,q) computes rows 4q..4q+3 for pair p as a float4.
// Weights staged in LDS transposed as float4-of-rows so the inner read is a
// conflict-free broadcast b128; x slice is a per-group broadcast.
// ---------------------------------------------------------------------------
constexpr int GPB = 8;  // (t,b) pairs per block

__global__ __launch_bounds__(256) void xg_kernel(
    const float* __restrict__ x, const float* __restrict__ Wih1,
    const float* __restrict__ bih1, const float* __restrict__ bhh1,
    float* __restrict__ xg)
{
    __shared__ float sW[G1 * F];      // sW[k*128 + r] = Wih1[r*32 + k]
    __shared__ float sb[G1];
    __shared__ float sx[GPB][F];

    const int tid = threadIdx.x;
    const int pair0 = blockIdx.x * GPB;

    for (int d = tid; d < G1 * F; d += 256) {
        const int k = d >> 7, r = d & 127;
        sW[d] = Wih1[r * F + k];
    }
    if (tid < G1) sb[tid] = bih1[tid] + bhh1[tid];
    {
        const int p = tid >> 5, k = tid & 31;
        sx[p][k] = x[(pair0 + p) * F + k];
    }
    __syncthreads();

    const int p = tid >> 5, q = tid & 31;
    const float4* sW4 = (const float4*)sW;       // sW4[k*32 + q] = rows 4q..4q+3 at col k
    float4 acc = ((const float4*)sb)[q];
#pragma unroll
    for (int k = 0; k < F; ++k) {
        const float xk = sx[p][k];
        const float4 wv = sW4[k * 32 + q];
        acc.x = fmaf(wv.x, xk, acc.x);
        acc.y = fmaf(wv.y, xk, acc.y);
        acc.z = fmaf(wv.z, xk, acc.z);
        acc.w = fmaf(wv.w, xk, acc.w);
    }
    ((float4*)xg)[(pair0 + p) * (G1 / 4) + q] = acc;
}

// ---------------------------------------------------------------------------
// Kernel B: recurrent scan, one 64-lane wave per batch element.
// Only 120 weight floats/lane (wh1a/wh1b 64, wi2 32, wh2/wi3/wh3 24).
// ---------------------------------------------------------------------------
__global__ __launch_bounds__(64, 1) void lstm3_rec_kernel(
    const float* __restrict__ xg,
    const float* __restrict__ Whh1,
    const float* __restrict__ Wih2, const float* __restrict__ Whh2,
    const float* __restrict__ bih2, const float* __restrict__ bhh2,
    const float* __restrict__ Wih3, const float* __restrict__ Whh3,
    const float* __restrict__ bih3, const float* __restrict__ bhh3,
    const float* __restrict__ mask1, const float* __restrict__ mask2,
    const float* __restrict__ mask3,
    float* __restrict__ out)
{
    const int lane = threadIdx.x;
    const int b = blockIdx.x;

    __shared__ __align__(16) float sh_h1[H1];
    __shared__ __align__(16) float sh_h2[H2];
    __shared__ __align__(16) float sh_h3[H3];

    // ---- weights / biases / masks in registers (120 floats) ----
    float wh1a[H1], wh1b[H1];
#pragma unroll
    for (int k = 0; k < H1; ++k) {
        wh1a[k] = Whh1[lane * H1 + k];          // row lane      (i|f half)
        wh1b[k] = Whh1[(lane + 64) * H1 + k];   // row lane+64   (g|o half)
    }
    const float cm1b = (lane < 32) ? 2.0f * SIG_CM : SIG_CM;
    const float ka1b = (lane < 32) ? 2.0f : 1.0f;
    const float kb1b = (lane < 32) ? -1.0f : 0.0f;

    const int r2 = lane & 31;
    float wi2[H1], wh2[H2];
#pragma unroll
    for (int k = 0; k < H1; ++k) wi2[k] = Wih2[r2 * H1 + k] * mask1[b * H1 + k];
#pragma unroll
    for (int k = 0; k < H2; ++k) wh2[k] = Whh2[r2 * H2 + k];
    const float bias2 = bih2[r2] + bhh2[r2];
    const int sec2 = r2 >> 3;
    const float cm2 = (sec2 == 2) ? 2.0f * SIG_CM : SIG_CM;
    const float ka2 = (sec2 == 2) ? 2.0f : 1.0f;
    const float kb2 = (sec2 == 2) ? -1.0f : 0.0f;

    float wi3[H2], wh3[H3];
#pragma unroll
    for (int k = 0; k < H2; ++k) wi3[k] = Wih3[r2 * H2 + k] * mask2[b * H2 + k];
#pragma unroll
    for (int k = 0; k < H3; ++k) wh3[k] = Whh3[r2 * H3 + k];
    const float bias3 = bih3[r2] + bhh3[r2];
    const float cm3 = cm2, ka3 = ka2, kb3 = kb2;  // same section layout

    const float m3 = mask3[b * H3 + (lane & 7)];

    // ---- state init ----
    float c1 = 0.f, c2 = 0.f, c3 = 0.f;
    if (lane < H1) sh_h1[lane] = 0.f;
    if (lane < H2) sh_h2[lane] = 0.f;
    if (lane < H3) sh_h3[lane] = 0.f;
    WAVE_SYNC();

    const int j = lane & 7;

    // xg prefetch: t=0 loaded ahead of the loop; inside the loop t+1 is
    // issued at the top and consumed next iteration (full-step latency cover).
    int xbase = b * G1 + lane;
    float xga = xg[xbase];            // row lane      at t=0
    float xgb = xg[xbase + 64];       // row lane+64   at t=0

    for (int t = 0; t < T; ++t) {
        const int tn = (t + 1 < T) ? (t + 1) : t;
        const int nbase = tn * (B * G1) + b * G1 + lane;
        const float xga_n = xg[nbase];
        const float xgb_n = xg[nbase + 64];

        // ---------------- layer 1 (x-projection precomputed) ----------------
        float a0A = 0.f, a0B = 0.f, a1A = 0.f, a1B = 0.f;
        {
            const float4* hp = (const float4*)sh_h1;
#pragma unroll
            for (int q = 0; q < 4; ++q) {
                const float4 hv = hp[q];
                FMA4(a0A, wh1a, hv, 4 * q);
                FMA4(a1A, wh1b, hv, 4 * q);
            }
#pragma unroll
            for (int q = 4; q < 8; ++q) {
                const float4 hv = hp[q];
                FMA4(a0B, wh1a, hv, 4 * q);
                FMA4(a1B, wh1b, hv, 4 * q);
            }
        }
        const float a0 = xga + (a0A + a0B);
        const float a1 = xgb + (a1A + a1B);
        const float g0 = act_f(a0, SIG_CM, 1.0f, 0.0f);  // i (l<32) / f (l>=32)
        const float g1 = act_f(a1, cm1b, ka1b, kb1b);    // g (l<32) / o (l>=32)
        const float f_ = __shfl_xor(g0, 32);
        const float o_ = __shfl_xor(g1, 32);
        c1 = fmaf(f_, c1, g0 * g1);
        const float h1 = o_ * tanh_fast(c1);

        WAVE_SYNC();
        if (lane < H1) sh_h1[lane] = h1;
        WAVE_SYNC();

        // ---------------- layer 2 (input = h1, mask folded) ----------------
        float a2A = 0.f, a2B = 0.f, a2h = 0.f;
        {
            const float4* hp = (const float4*)sh_h1;
#pragma unroll
            for (int q = 0; q < 4; ++q) { const float4 hv = hp[q]; FMA4(a2A, wi2, hv, 4 * q); }
#pragma unroll
            for (int q = 4; q < 8; ++q) { const float4 hv = hp[q]; FMA4(a2B, wi2, hv, 4 * q); }
            const float4* h2p = (const float4*)sh_h2;
            const float4 v0 = h2p[0], v1 = h2p[1];
            FMA4(a2h, wh2, v0, 0);
            FMA4(a2h, wh2, v1, 4);
        }
        const float a2 = bias2 + a2A + (a2B + a2h);
        const float r2v = act_f(a2, cm2, ka2, kb2);
        const float i2 = __shfl(r2v, j);
        const float f2 = __shfl(r2v, j + 8);
        const float g2 = __shfl(r2v, j + 16);
        const float o2 = __shfl(r2v, j + 24);
        c2 = fmaf(f2, c2, i2 * g2);
        const float h2 = o2 * tanh_fast(c2);

        WAVE_SYNC();
        if (lane < H2) sh_h2[lane] = h2;
        WAVE_SYNC();

        // ---------------- layer 3 (input = h2, mask folded) ----------------
        float a3x = 0.f, a3h = 0.f;
        {
            const float4* h2p = (const float4*)sh_h2;
            const float4* h3p = (const float4*)sh_h3;
            const float4 u0 = h2p[0], u1 = h2p[1];
            FMA4(a3x, wi3, u0, 0);
            FMA4(a3x, wi3, u1, 4);
            const float4 w0 = h3p[0], w1 = h3p[1];
            FMA4(a3h, wh3, w0, 0);
            FMA4(a3h, wh3, w1, 4);
        }
        const float a3 = bias3 + a3x + a3h;
        const float r3v = act_f(a3, cm3, ka3, kb3);
        const float i3 = __shfl(r3v, j);
        const float f3 = __shfl(r3v, j + 8);
        const float g3 = __shfl(r3v, j + 16);
        const float o3 = __shfl(r3v, j + 24);
        c3 = fmaf(f3, c3, i3 * g3);
        const float h3 = o3 * tanh_fast(c3);

        if (lane < H3) out[t * (B * H3) + b * H3 + lane] = h3 * m3;

        WAVE_SYNC();
        if (lane < H3) sh_h3[lane] = h3;
        WAVE_SYNC();

        xga = xga_n;
        xgb = xgb_n;
    }
}

// ---------------------------------------------------------------------------
// Fallback (R3 structure, self-contained, no workspace): used iff ws_size is
// too small for xg. Known-good at ~967 us.
// ---------------------------------------------------------------------------
__global__ __launch_bounds__(64, 1) void lstm3_fallback_kernel(
    const float* __restrict__ x,
    const float* __restrict__ Wih1, const float* __restrict__ Whh1,
    const float* __restrict__ bih1, const float* __restrict__ bhh1,
    const float* __restrict__ Wih2, const float* __restrict__ Whh2,
    const float* __restrict__ bih2, const float* __restrict__ bhh2,
    const float* __restrict__ Wih3, const float* __restrict__ Whh3,
    const float* __restrict__ bih3, const float* __restrict__ bhh3,
    const float* __restrict__ mask1, const float* __restrict__ mask2,
    const float* __restrict__ mask3,
    float* __restrict__ out)
{
    const int lane = threadIdx.x;
    const int b = blockIdx.x;

    __shared__ __align__(16) float sh_x[2][F];
    __shared__ __align__(16) float sh_h1[H1];
    __shared__ __align__(16) float sh_h2[H2];
    __shared__ __align__(16) float sh_h3[H3];

    const int r0 = lane, r1 = lane + 64;
    float wi1a[F], wh1a[H1], wi1b[F], wh1b[H1];
#pragma unroll
    for (int k = 0; k < F; ++k) { wi1a[k] = Wih1[r0 * F + k]; wi1b[k] = Wih1[r1 * F + k]; }
#pragma unroll
    for (int k = 0; k < H1; ++k) { wh1a[k] = Whh1[r0 * H1 + k]; wh1b[k] = Whh1[r1 * H1 + k]; }
    const float bias0 = bih1[r0] + bhh1[r0];
    const float bias1 = bih1[r1] + bhh1[r1];
    const float cm1b = (lane < 32) ? 2.0f * SIG_CM : SIG_CM;
    const float ka1b = (lane < 32) ? 2.0f : 1.0f;
    const float kb1b = (lane < 32) ? -1.0f : 0.0f;

    const int r2 = lane & 31;
    float wi2[H1], wh2[H2];
#pragma unroll
    for (int k = 0; k < H1; ++k) wi2[k] = Wih2[r2 * H1 + k] * mask1[b * H1 + k];
#pragma unroll
    for (int k = 0; k < H2; ++k) wh2[k] = Whh2[r2 * H2 + k];
    const float bias2 = bih2[r2] + bhh2[r2];
    const int sec2 = r2 >> 3;
    const float cm2 = (sec2 == 2) ? 2.0f * SIG_CM : SIG_CM;
    const float ka2 = (sec2 == 2) ? 2.0f : 1.0f;
    const float kb2 = (sec2 == 2) ? -1.0f : 0.0f;

    float wi3[H2], wh3[H3];
#pragma unroll
    for (int k = 0; k < H2; ++k) wi3[k] = Wih3[r2 * H2 + k] * mask2[b * H2 + k];
#pragma unroll
    for (int k = 0; k < H3; ++k) wh3[k] = Whh3[r2 * H3 + k];
    const float bias3 = bih3[r2] + bhh3[r2];

    const float m3 = mask3[b * H3 + (lane & 7)];

    float c1 = 0.f, c2 = 0.f, c3 = 0.f;
    if (lane < F) sh_x[0][lane] = x[b * F + lane];
    if (lane < H1) sh_h1[lane] = 0.f;
    if (lane < H2) sh_h2[lane] = 0.f;
    if (lane < H3) sh_h3[lane] = 0.f;
    WAVE_SYNC();

    const int j = lane & 7;

    for (int t = 0; t < T; ++t) {
        const int cur = t & 1, nxt = cur ^ 1;
        float xnext = 0.f;
        {
            const int tn = (t + 1 < T) ? (t + 1) : t;
            if (lane < F) xnext = x[tn * (B * F) + b * F + lane];
        }
        float a0x = 0.f, a0h = 0.f, a1x = 0.f, a1h = 0.f;
        {
            const float4* xp = (const float4*)sh_x[cur];
            const float4* hp = (const float4*)sh_h1;
#pragma unroll
            for (int q = 0; q < 8; ++q) {
                float4 xv = xp[q], hv = hp[q];
                FMA4(a0x, wi1a, xv, 4 * q);
                FMA4(a0h, wh1a, hv, 4 * q);
                FMA4(a1x, wi1b, xv, 4 * q);
                FMA4(a1h, wh1b, hv, 4 * q);
            }
        }
        const float a0 = bias0 + a0x + a0h;
        const float a1 = bias1 + a1x + a1h;
        const float g0 = act_f(a0, SIG_CM, 1.0f, 0.0f);
        const float g1 = act_f(a1, cm1b, ka1b, kb1b);
        const float f_ = __shfl_xor(g0, 32);
        const float o_ = __shfl_xor(g1, 32);
        c1 = fmaf(f_, c1, g0 * g1);
        const float h1 = o_ * tanh_fast(c1);

        WAVE_SYNC();
        if (lane < H1) sh_h1[lane] = h1;
        if (lane < F) sh_x[nxt][lane] = xnext;
        WAVE_SYNC();

        float a2x = 0.f, a2h = 0.f;
        {
            const float4* hp = (const float4*)sh_h1;
#pragma unroll
            for (int q = 0; q < 8; ++q) { float4 hv = hp[q]; FMA4(a2x, wi2, hv, 4 * q); }
            const float4* h2p = (const float4*)sh_h2;
            float4 v0 = h2p[0], v1 = h2p[1];
            FMA4(a2h, wh2, v0, 0);
            FMA4(a2h, wh2, v1, 4);
        }
        const float a2 = bias2 + a2x + a2h;
        const float r2v = act_f(a2, cm2, ka2, kb2);
        const float i2 = __shfl(r2v, j);
        const float f2 = __shfl(r2v, j + 8);
        const float g2 = __shfl(r2v, j + 16);
        const float o2 = __shfl(r2v, j + 24);
        c2 = fmaf(f2, c2, i2 * g2);
        const float h2 = o2 * tanh_fast(c2);

        WAVE_SYNC();
        if (lane < H2) sh_h2[lane] = h2;
        WAVE_SYNC();

        float a3x = 0.f, a3h = 0.f;
        {
            const float4* h2p = (const float4*)sh_h2;
            const float4* h3p = (const float4*)sh_h3;
            float4 u0 = h2p[0], u1 = h2p[1];
            FMA4(a3x, wi3, u0, 0);
            FMA4(a3x, wi3, u1, 4);
            float4 w0 = h3p[0], w1 = h3p[1];
            FMA4(a3h, wh3, w0, 0);
            FMA4(a3h, wh3, w1, 4);
        }
        const float a3 = bias3 + a3x + a3h;
        const float r3v = act_f(a3, cm2, ka2, kb2);
        const float i3 = __shfl(r3v, j);
        const float f3 = __shfl(r3v, j + 8);
        const float g3 = __shfl(r3v, j + 16);
        const float o3 = __shfl(r3v, j + 24);
        c3 = fmaf(f3, c3, i3 * g3);
        const float h3 = o3 * tanh_fast(c3);

        if (lane < H3) out[t * (B * H3) + b * H3 + lane] = h3 * m3;

        WAVE_SYNC();
        if (lane < H3) sh_h3[lane] = h3;
        WAVE_SYNC();
    }
}

extern "C" void kernel_launch(void* const* d_in, const int* in_sizes, int n_in,
                              void* d_out, int out_size, void* d_ws, size_t ws_size,
                              hipStream_t stream) {
    (void)in_sizes; (void)n_in; (void)out_size;
    const float* x     = (const float*)d_in[0];
    const float* Wih1  = (const float*)d_in[1];
    const float* Whh1  = (const float*)d_in[2];
    const float* bih1  = (const float*)d_in[3];
    const float* bhh1  = (const float*)d_in[4];
    const float* Wih2  = (const float*)d_in[5];
    const float* Whh2  = (const float*)d_in[6];
    const float* bih2  = (const float*)d_in[7];
    const float* bhh2  = (const float*)d_in[8];
    const float* Wih3  = (const float*)d_in[9];
    const float* Whh3  = (const float*)d_in[10];
    const float* bih3  = (const float*)d_in[11];
    const float* bhh3  = (const float*)d_in[12];
    const float* mask1 = (const float*)d_in[13];
    const float* mask2 = (const float*)d_in[14];
    const float* mask3 = (const float*)d_in[15];
    float* out = (float*)d_out;

    const size_t xg_bytes = (size_t)T * B * G1 * sizeof(float);  // 256 MB
    if (ws_size >= xg_bytes) {
        float* xg = (float*)d_ws;
        xg_kernel<<<dim3(T * B / GPB), dim3(256), 0, stream>>>(
            x, Wih1, bih1, bhh1, xg);
        lstm3_rec_kernel<<<dim3(B), dim3(64), 0, stream>>>(
            xg, Whh1, Wih2, Whh2, bih2, bhh2,
            Wih3, Whh3, bih3, bhh3, mask1, mask2, mask3, out);
    } else {
        lstm3_fallback_kernel<<<dim3(B), dim3(64), 0, stream>>>(
            x, Wih1, Whh1, bih1, bhh1, Wih2, Whh2, bih2, bhh2,
            Wih3, Whh3, bih3, bhh3, mask1, mask2, mask3, out);
    }
}

// Round 6
// 917.575 us; speedup vs baseline: 1.5700x; 1.5700x over previous
//
#include <hip/hip_runtime.h>

// 3-layer LSTM (T=1024,B=512,F=32,H1=32,H2=8,H3=8) + locked dropout.
//
// R6: STAGE-SKEWED PIPELINE WITH HOISTED LDS READS.
// R5 evidence: rec kernel latency-bound (VALUBusy 18%, 2110 cyc/step), issue
// count irrelevant. The 3 layers serialize through LDS round trips + FMA +
// shuffle chains. Fix: iteration i computes L1(i), L2(i-1), L3(i-2). ALL LDS
// reads are hoisted to the top of the body (L1+L2 share h1(i-1); L2+L3 share
// h2(i-2)), all writes sink to the bottom -> no intra-iteration LDS aliasing,
// stages are independent dataflow -> critical path = 1 LDS round trip +
// max(stage chain) instead of the sum of 3 stages.
// Also: xg pre-pass rebuilt (64 pairs/block, coalesced transposed staging) —
// R5's version burned ~540 us re-staging weights per 8-pair block.

constexpr int T = 1024, B = 512, F = 32;
constexpr int H1 = 32, H2 = 8, H3 = 8;
constexpr int G1 = 4 * H1;  // 128 gate rows, layer 1

#define WAVE_SYNC() asm volatile("" ::: "memory")

#if __has_builtin(__builtin_amdgcn_rcpf)
#define RCPF(x) __builtin_amdgcn_rcpf(x)
#else
#define RCPF(x) (1.0f / (x))
#endif
#if __has_builtin(__builtin_amdgcn_exp2f)
#define EXP2F(x) __builtin_amdgcn_exp2f(x)
#else
#define EXP2F(x) exp2f(x)
#endif

#define SIG_CM (-1.4426950408889634f)

__device__ __forceinline__ float act_f(float v, float cm, float ka, float kb) {
    return fmaf(ka, RCPF(1.0f + EXP2F(v * cm)), kb);
}
__device__ __forceinline__ float tanh_fast(float v) {
    return fmaf(2.0f, RCPF(1.0f + EXP2F(v * (2.0f * SIG_CM))), -1.0f);
}

// macro params avoid float4 member names x/y/z/w (R1 lesson)
#define FMA4(ACC, WARR, VEC, BASE)                                             \
    ACC = fmaf(WARR[(BASE) + 0], VEC.x, ACC);                                  \
    ACC = fmaf(WARR[(BASE) + 1], VEC.y, ACC);                                  \
    ACC = fmaf(WARR[(BASE) + 2], VEC.z, ACC);                                  \
    ACC = fmaf(WARR[(BASE) + 3], VEC.w, ACC);

// ---------------------------------------------------------------------------
// Kernel A: xg[(t*B+b)*128 + r] = sum_k Wih1[r][k]*x[t][b][k] + bih1[r]+bhh1[r]
// 64 pairs/block (8192 blocks, 256 thr): 16 KB weight stage amortized over
// 32 KB of output. Weight load coalesced (transposed into padded LDS).
// ---------------------------------------------------------------------------
constexpr int GPB = 64;        // (t,b) pairs per block
constexpr int WPAD = 132;      // row stride of transposed weight tile (pad 4)

__global__ __launch_bounds__(256) void xg_kernel(
    const float* __restrict__ x, const float* __restrict__ Wih1,
    const float* __restrict__ bih1, const float* __restrict__ bhh1,
    float* __restrict__ xg)
{
    __shared__ __align__(16) float sW[F * WPAD];  // sW[k*WPAD + r] = Wih1[r*32+k]
    __shared__ __align__(16) float sb[G1];
    __shared__ __align__(16) float sx[GPB * F];

    const int tid = threadIdx.x;
    const int pair0 = blockIdx.x * GPB;

    // coalesced weight load (consecutive tid -> consecutive k), transposed store
    for (int d = tid; d < G1 * F; d += 256) {
        const int r = d >> 5, k = d & 31;
        sW[k * WPAD + r] = Wih1[d];           // Wih1[d] == Wih1[r*32 + k]
    }
    if (tid < G1) sb[tid] = bih1[tid] + bhh1[tid];
    for (int d = tid; d < GPB * F; d += 256)
        sx[d] = x[pair0 * F + d];             // fully coalesced
    __syncthreads();

    for (int u = tid; u < GPB * (G1 / 4); u += 256) {
        const int p = u >> 5, q = u & 31;     // pair p, rows 4q..4q+3
        float4 acc = ((const float4*)sb)[q];
#pragma unroll
        for (int k = 0; k < F; ++k) {
            const float xk = sx[p * F + k];
            const float4 wv = *(const float4*)(sW + k * WPAD + 4 * q);
            acc.x = fmaf(wv.x, xk, acc.x);
            acc.y = fmaf(wv.y, xk, acc.y);
            acc.z = fmaf(wv.z, xk, acc.z);
            acc.w = fmaf(wv.w, xk, acc.w);
        }
        ((float4*)xg)[(pair0 + p) * (G1 / 4) + q] = acc;
    }
}

// ---------------------------------------------------------------------------
// Kernel B: skewed recurrent scan, one 64-lane wave per batch element.
// Iteration i: L1(i) | L2(i-1) | L3(i-2). Parity-buffered h-state.
// ---------------------------------------------------------------------------
__global__ __launch_bounds__(64, 1) void lstm3_rec_kernel(
    const float* __restrict__ xg,
    const float* __restrict__ Whh1,
    const float* __restrict__ Wih2, const float* __restrict__ Whh2,
    const float* __restrict__ bih2, const float* __restrict__ bhh2,
    const float* __restrict__ Wih3, const float* __restrict__ Whh3,
    const float* __restrict__ bih3, const float* __restrict__ bhh3,
    const float* __restrict__ mask1, const float* __restrict__ mask2,
    const float* __restrict__ mask3,
    float* __restrict__ out)
{
    const int lane = threadIdx.x;
    const int b = blockIdx.x;

    __shared__ __align__(16) float sh_h1[2][H1];
    __shared__ __align__(16) float sh_h2[2][H2];
    __shared__ __align__(16) float sh_h3[2][H3];

    // ---- weights / biases / masks in registers ----
    float wh1a[H1], wh1b[H1];
#pragma unroll
    for (int k = 0; k < H1; ++k) {
        wh1a[k] = Whh1[lane * H1 + k];          // row lane      (i|f half)
        wh1b[k] = Whh1[(lane + 64) * H1 + k];   // row lane+64   (g|o half)
    }
    const float cm1b = (lane < 32) ? 2.0f * SIG_CM : SIG_CM;
    const float ka1b = (lane < 32) ? 2.0f : 1.0f;
    const float kb1b = (lane < 32) ? -1.0f : 0.0f;

    const int r2 = lane & 31;
    float wi2[H1], wh2[H2];
#pragma unroll
    for (int k = 0; k < H1; ++k) wi2[k] = Wih2[r2 * H1 + k] * mask1[b * H1 + k];
#pragma unroll
    for (int k = 0; k < H2; ++k) wh2[k] = Whh2[r2 * H2 + k];
    const float bias2 = bih2[r2] + bhh2[r2];
    const int sec2 = r2 >> 3;
    const float cm2 = (sec2 == 2) ? 2.0f * SIG_CM : SIG_CM;
    const float ka2 = (sec2 == 2) ? 2.0f : 1.0f;
    const float kb2 = (sec2 == 2) ? -1.0f : 0.0f;

    float wi3[H2], wh3[H3];
#pragma unroll
    for (int k = 0; k < H2; ++k) wi3[k] = Wih3[r2 * H2 + k] * mask2[b * H2 + k];
#pragma unroll
    for (int k = 0; k < H3; ++k) wh3[k] = Whh3[r2 * H3 + k];
    const float bias3 = bih3[r2] + bhh3[r2];

    const float m3 = mask3[b * H3 + (lane & 7)];

    // ---- state init (both parities zero) ----
    float c1 = 0.f, c2 = 0.f, c3 = 0.f;
    if (lane < H1) { sh_h1[0][lane] = 0.f; sh_h1[1][lane] = 0.f; }
    if (lane < H2) { sh_h2[0][lane] = 0.f; sh_h2[1][lane] = 0.f; }
    if (lane < H3) { sh_h3[0][lane] = 0.f; sh_h3[1][lane] = 0.f; }
    WAVE_SYNC();

    const int j = lane & 7;
    const int xbase = b * G1 + lane;

    // xg prefetch, distance 2
    float xa0 = xg[0 * (B * G1) + xbase];
    float xb0 = xg[0 * (B * G1) + xbase + 64];
    float xa1 = xg[1 * (B * G1) + xbase];
    float xb1 = xg[1 * (B * G1) + xbase + 64];

    for (int i = 0; i <= T + 1; ++i) {
        const int par = i & 1;
        const bool do2 = (i >= 1);
        const bool do3 = (i >= 2);
        const int t3 = i - 2;

        // ---- xg prefetch for i+2 (clamped) ----
        const int tpre = (i + 2 < T) ? (i + 2) : (T - 1);
        const int pidx = tpre * (B * G1) + xbase;
        const float xa2 = xg[pidx];
        const float xb2 = xg[pidx + 64];

        // ---- ALL LDS reads hoisted; no writes have happened this iteration,
        //      so the three stage dataflows below are fully independent ----
        const float4* h1p = (const float4*)sh_h1[par ^ 1];   // h1(i-1)
        float4 h1v0 = h1p[0], h1v1 = h1p[1], h1v2 = h1p[2], h1v3 = h1p[3];
        float4 h1v4 = h1p[4], h1v5 = h1p[5], h1v6 = h1p[6], h1v7 = h1p[7];
        const float4* h2p = (const float4*)sh_h2[par];        // h2(i-2)
        const float4 h2v0 = h2p[0], h2v1 = h2p[1];
        const float4* h3p = (const float4*)sh_h3[par ^ 1];    // h3(i-3)
        const float4 h3v0 = h3p[0], h3v1 = h3p[1];

        // ================= L1(t1=min(i,T-1)): rows lane & lane+64 ==========
        float a0A = 0.f, a0B = 0.f, a0C = 0.f, a0D = 0.f;
        float a1A = 0.f, a1B = 0.f, a1C = 0.f, a1D = 0.f;
        FMA4(a0A, wh1a, h1v0, 0);  FMA4(a0B, wh1a, h1v1, 4);
        FMA4(a0C, wh1a, h1v2, 8);  FMA4(a0D, wh1a, h1v3, 12);
        FMA4(a0A, wh1a, h1v4, 16); FMA4(a0B, wh1a, h1v5, 20);
        FMA4(a0C, wh1a, h1v6, 24); FMA4(a0D, wh1a, h1v7, 28);
        FMA4(a1A, wh1b, h1v0, 0);  FMA4(a1B, wh1b, h1v1, 4);
        FMA4(a1C, wh1b, h1v2, 8);  FMA4(a1D, wh1b, h1v3, 12);
        FMA4(a1A, wh1b, h1v4, 16); FMA4(a1B, wh1b, h1v5, 20);
        FMA4(a1C, wh1b, h1v6, 24); FMA4(a1D, wh1b, h1v7, 28);
        const float a0 = xa0 + (a0A + a0B) + (a0C + a0D);
        const float a1 = xb0 + (a1A + a1B) + (a1C + a1D);
        const float g0 = act_f(a0, SIG_CM, 1.0f, 0.0f);  // i (l<32) / f (l>=32)
        const float g1 = act_f(a1, cm1b, ka1b, kb1b);    // g (l<32) / o (l>=32)
        const float f_ = __shfl_xor(g0, 32);
        const float o_ = __shfl_xor(g1, 32);
        c1 = fmaf(f_, c1, g0 * g1);
        const float h1new = o_ * tanh_fast(c1);

        // ================= L2(t2=i-1): input h1(i-1), rec h2(i-2) ==========
        float a2A = 0.f, a2B = 0.f, a2C = 0.f, a2D = 0.f;
        FMA4(a2A, wi2, h1v0, 0);  FMA4(a2B, wi2, h1v1, 4);
        FMA4(a2C, wi2, h1v2, 8);  FMA4(a2D, wi2, h1v3, 12);
        FMA4(a2A, wi2, h1v4, 16); FMA4(a2B, wi2, h1v5, 20);
        FMA4(a2C, wi2, h1v6, 24); FMA4(a2D, wi2, h1v7, 28);
        float a2h = 0.f;
        FMA4(a2h, wh2, h2v0, 0);
        FMA4(a2h, wh2, h2v1, 4);
        const float a2 = bias2 + (a2A + a2B) + (a2C + (a2D + a2h));
        const float r2v = act_f(a2, cm2, ka2, kb2);
        const float i2 = __shfl(r2v, j);
        const float f2 = __shfl(r2v, j + 8);
        const float g2 = __shfl(r2v, j + 16);
        const float o2 = __shfl(r2v, j + 24);
        c2 = do2 ? fmaf(f2, c2, i2 * g2) : 0.0f;
        const float h2new = o2 * tanh_fast(c2);

        // ================= L3(t3=i-2): input h2(i-2), rec h3(i-3) ==========
        float a3x = 0.f, a3h = 0.f;
        FMA4(a3x, wi3, h2v0, 0);
        FMA4(a3x, wi3, h2v1, 4);
        FMA4(a3h, wh3, h3v0, 0);
        FMA4(a3h, wh3, h3v1, 4);
        const float a3 = bias3 + a3x + a3h;
        const float r3v = act_f(a3, cm2, ka2, kb2);  // same section layout as L2
        const float i3 = __shfl(r3v, j);
        const float f3 = __shfl(r3v, j + 8);
        const float g3 = __shfl(r3v, j + 16);
        const float o3 = __shfl(r3v, j + 24);
        c3 = do3 ? fmaf(f3, c3, i3 * g3) : 0.0f;
        const float h3new = o3 * tanh_fast(c3);

        if (do3 && lane < H3)
            out[t3 * (B * H3) + b * H3 + lane] = h3new * m3;

        // ---- writes sink to the bottom ----
        if (lane < H1) sh_h1[par][lane] = h1new;                 // h1(i)
        if (do2 && lane < H2) sh_h2[par ^ 1][lane] = h2new;      // h2(i-1)
        if (do3 && lane < H3) sh_h3[par][lane] = h3new;          // h3(i-2)

        // shift xg prefetch registers
        xa0 = xa1; xb0 = xb1;
        xa1 = xa2; xb1 = xb2;
    }
}

// ---------------------------------------------------------------------------
// Fallback (R3 structure, self-contained, no workspace): used iff ws_size is
// too small for xg. Known-good.
// ---------------------------------------------------------------------------
__global__ __launch_bounds__(64, 1) void lstm3_fallback_kernel(
    const float* __restrict__ x,
    const float* __restrict__ Wih1, const float* __restrict__ Whh1,
    const float* __restrict__ bih1, const float* __restrict__ bhh1,
    const float* __restrict__ Wih2, const float* __restrict__ Whh2,
    const float* __restrict__ bih2, const float* __restrict__ bhh2,
    const float* __restrict__ Wih3, const float* __restrict__ Whh3,
    const float* __restrict__ bih3, const float* __restrict__ bhh3,
    const float* __restrict__ mask1, const float* __restrict__ mask2,
    const float* __restrict__ mask3,
    float* __restrict__ out)
{
    const int lane = threadIdx.x;
    const int b = blockIdx.x;

    __shared__ __align__(16) float sh_x[2][F];
    __shared__ __align__(16) float sh_h1[H1];
    __shared__ __align__(16) float sh_h2[H2];
    __shared__ __align__(16) float sh_h3[H3];

    const int r0 = lane, r1 = lane + 64;
    float wi1a[F], wh1a[H1], wi1b[F], wh1b[H1];
#pragma unroll
    for (int k = 0; k < F; ++k) { wi1a[k] = Wih1[r0 * F + k]; wi1b[k] = Wih1[r1 * F + k]; }
#pragma unroll
    for (int k = 0; k < H1; ++k) { wh1a[k] = Whh1[r0 * H1 + k]; wh1b[k] = Whh1[r1 * H1 + k]; }
    const float bias0 = bih1[r0] + bhh1[r0];
    const float bias1 = bih1[r1] + bhh1[r1];
    const float cm1b = (lane < 32) ? 2.0f * SIG_CM : SIG_CM;
    const float ka1b = (lane < 32) ? 2.0f : 1.0f;
    const float kb1b = (lane < 32) ? -1.0f : 0.0f;

    const int r2 = lane & 31;
    float wi2[H1], wh2[H2];
#pragma unroll
    for (int k = 0; k < H1; ++k) wi2[k] = Wih2[r2 * H1 + k] * mask1[b * H1 + k];
#pragma unroll
    for (int k = 0; k < H2; ++k) wh2[k] = Whh2[r2 * H2 + k];
    const float bias2 = bih2[r2] + bhh2[r2];
    const int sec2 = r2 >> 3;
    const float cm2 = (sec2 == 2) ? 2.0f * SIG_CM : SIG_CM;
    const float ka2 = (sec2 == 2) ? 2.0f : 1.0f;
    const float kb2 = (sec2 == 2) ? -1.0f : 0.0f;

    float wi3[H2], wh3[H3];
#pragma unroll
    for (int k = 0; k < H2; ++k) wi3[k] = Wih3[r2 * H2 + k] * mask2[b * H2 + k];
#pragma unroll
    for (int k = 0; k < H3; ++k) wh3[k] = Whh3[r2 * H3 + k];
    const float bias3 = bih3[r2] + bhh3[r2];

    const float m3 = mask3[b * H3 + (lane & 7)];

    float c1 = 0.f, c2 = 0.f, c3 = 0.f;
    if (lane < F) sh_x[0][lane] = x[b * F + lane];
    if (lane < H1) sh_h1[lane] = 0.f;
    if (lane < H2) sh_h2[lane] = 0.f;
    if (lane < H3) sh_h3[lane] = 0.f;
    WAVE_SYNC();

    const int j = lane & 7;

    for (int t = 0; t < T; ++t) {
        const int cur = t & 1, nxt = cur ^ 1;
        float xnext = 0.f;
        {
            const int tn = (t + 1 < T) ? (t + 1) : t;
            if (lane < F) xnext = x[tn * (B * F) + b * F + lane];
        }
        float a0x = 0.f, a0h = 0.f, a1x = 0.f, a1h = 0.f;
        {
            const float4* xp = (const float4*)sh_x[cur];
            const float4* hp = (const float4*)sh_h1;
#pragma unroll
            for (int q = 0; q < 8; ++q) {
                float4 xv = xp[q], hv = hp[q];
                FMA4(a0x, wi1a, xv, 4 * q);
                FMA4(a0h, wh1a, hv, 4 * q);
                FMA4(a1x, wi1b, xv, 4 * q);
                FMA4(a1h, wh1b, hv, 4 * q);
            }
        }
        const float a0 = bias0 + a0x + a0h;
        const float a1 = bias1 + a1x + a1h;
        const float g0 = act_f(a0, SIG_CM, 1.0f, 0.0f);
        const float g1 = act_f(a1, cm1b, ka1b, kb1b);
        const float f_ = __shfl_xor(g0, 32);
        const float o_ = __shfl_xor(g1, 32);
        c1 = fmaf(f_, c1, g0 * g1);
        const float h1 = o_ * tanh_fast(c1);

        WAVE_SYNC();
        if (lane < H1) sh_h1[lane] = h1;
        if (lane < F) sh_x[nxt][lane] = xnext;
        WAVE_SYNC();

        float a2x = 0.f, a2h = 0.f;
        {
            const float4* hp = (const float4*)sh_h1;
#pragma unroll
            for (int q = 0; q < 8; ++q) { float4 hv = hp[q]; FMA4(a2x, wi2, hv, 4 * q); }
            const float4* h2p = (const float4*)sh_h2;
            float4 v0 = h2p[0], v1 = h2p[1];
            FMA4(a2h, wh2, v0, 0);
            FMA4(a2h, wh2, v1, 4);
        }
        const float a2 = bias2 + a2x + a2h;
        const float r2v = act_f(a2, cm2, ka2, kb2);
        const float i2 = __shfl(r2v, j);
        const float f2 = __shfl(r2v, j + 8);
        const float g2 = __shfl(r2v, j + 16);
        const float o2 = __shfl(r2v, j + 24);
        c2 = fmaf(f2, c2, i2 * g2);
        const float h2 = o2 * tanh_fast(c2);

        WAVE_SYNC();
        if (lane < H2) sh_h2[lane] = h2;
        WAVE_SYNC();

        float a3x = 0.f, a3h = 0.f;
        {
            const float4* h2p = (const float4*)sh_h2;
            const float4* h3p = (const float4*)sh_h3;
            float4 u0 = h2p[0], u1 = h2p[1];
            FMA4(a3x, wi3, u0, 0);
            FMA4(a3x, wi3, u1, 4);
            float4 w0 = h3p[0], w1 = h3p[1];
            FMA4(a3h, wh3, w0, 0);
            FMA4(a3h, wh3, w1, 4);
        }
        const float a3 = bias3 + a3x + a3h;
        const float r3v = act_f(a3, cm2, ka2, kb2);
        const float i3 = __shfl(r3v, j);
        const float f3 = __shfl(r3v, j + 8);
        const float g3 = __shfl(r3v, j + 16);
        const float o3 = __shfl(r3v, j + 24);
        c3 = fmaf(f3, c3, i3 * g3);
        const float h3 = o3 * tanh_fast(c3);

        if (lane < H3) out[t * (B * H3) + b * H3 + lane] = h3 * m3;

        WAVE_SYNC();
        if (lane < H3) sh_h3[lane] = h3;
        WAVE_SYNC();
    }
}

extern "C" void kernel_launch(void* const* d_in, const int* in_sizes, int n_in,
                              void* d_out, int out_size, void* d_ws, size_t ws_size,
                              hipStream_t stream) {
    (void)in_sizes; (void)n_in; (void)out_size;
    const float* x     = (const float*)d_in[0];
    const float* Wih1  = (const float*)d_in[1];
    const float* Whh1  = (const float*)d_in[2];
    const float* bih1  = (const float*)d_in[3];
    const float* bhh1  = (const float*)d_in[4];
    const float* Wih2  = (const float*)d_in[5];
    const float* Whh2  = (const float*)d_in[6];
    const float* bih2  = (const float*)d_in[7];
    const float* bhh2  = (const float*)d_in[8];
    const float* Wih3  = (const float*)d_in[9];
    const float* Whh3  = (const float*)d_in[10];
    const float* bih3  = (const float*)d_in[11];
    const float* bhh3  = (const float*)d_in[12];
    const float* mask1 = (const float*)d_in[13];
    const float* mask2 = (const float*)d_in[14];
    const float* mask3 = (const float*)d_in[15];
    float* out = (float*)d_out;

    const size_t xg_bytes = (size_t)T * B * G1 * sizeof(float);  // 256 MB
    if (ws_size >= xg_bytes) {
        float* xg = (float*)d_ws;
        xg_kernel<<<dim3(T * B / GPB), dim3(256), 0, stream>>>(
            x, Wih1, bih1, bhh1, xg);
        lstm3_rec_kernel<<<dim3(B), dim3(64), 0, stream>>>(
            xg, Whh1, Wih2, Whh2, bih2, bhh2,
            Wih3, Whh3, bih3, bhh3, mask1, mask2, mask3, out);
    } else {
        lstm3_fallback_kernel<<<dim3(B), dim3(64), 0, stream>>>(
            x, Wih1, Whh1, bih1, bhh1, Wih2, Whh2, bih2, bhh2,
            Wih3, Whh3, bih3, bhh3, mask1, mask2, mask3, out);
    }
}